// Round 4
// baseline (395.761 us; speedup 1.0000x reference)
//
#include <hip/hip_runtime.h>
#include <hip/hip_bf16.h>

#define Bn   64
#define Tn   2048
#define ENCD 512
#define DECD 1024
#define HIDD 128
#define TT   32
#define NCH  (Tn / TT)     // 64 chunks per batch
#define LROW 520           // bf16 elems per LDS row: 512 + 8 pad

typedef __attribute__((ext_vector_type(8))) short bf16x8;
typedef __attribute__((ext_vector_type(4))) float f32x4;

__device__ __forceinline__ unsigned short f2bf(float f) {
    union { float f; unsigned u; } v; v.f = f;
    unsigned r = v.u + 0x7FFFu + ((v.u >> 16) & 1u);   // RNE
    return (unsigned short)(r >> 16);
}
__device__ __forceinline__ float bf2f(unsigned short s) {
    union { unsigned u; float f; } v; v.u = ((unsigned)s) << 16;
    return v.f;
}
__device__ __forceinline__ float tanh_fast(float x) {
    float xa = fminf(fmaxf(x, -10.f), 10.f);
    float e = __expf(2.f * xa);
    return (e - 1.f) / (e + 1.f);
}
// nontemporal load via native clang vector type (HIP_vector_type is rejected)
__device__ __forceinline__ f32x4 ldnt4(const float* p) {
    return __builtin_nontemporal_load((const f32x4*)p);
}

// ---------------------------------------------------------------------------
// Kernel 1: qb[b][h] = dec[b]·W_w[h] + V_b[h]   and   Vbf = bf16(V_w)
// grid = 512 (GEMV) + 64 (convert), block = 256
// ---------------------------------------------------------------------------
__global__ __launch_bounds__(256) void prep(
    const float* __restrict__ dec, const float* __restrict__ Ww,
    const float* __restrict__ Vb,  const float* __restrict__ Vw,
    float* __restrict__ qb, unsigned short* __restrict__ Vbf)
{
    const int blk = blockIdx.x, tid = threadIdx.x;
    if (blk < 512) {
        // GEMV: block = (b, hg); 16 h per block, 16 lanes per h
        const int b = blk >> 3, hg = blk & 7;
        const int h_local = tid >> 4, seg = tid & 15;
        const int h = hg * 16 + h_local;
        const float* w = Ww + (size_t)h * DECD;
        const float* d = dec + (size_t)b * DECD;
        float acc = 0.f;
        #pragma unroll
        for (int j = 0; j < 16; ++j) {
            int f4 = j * 16 + seg;               // coalesced within 16-lane seg
            f32x4 a = *(const f32x4*)(d + f4 * 4);
            f32x4 bb = *(const f32x4*)(w + f4 * 4);
            acc += a.x * bb.x + a.y * bb.y + a.z * bb.z + a.w * bb.w;
        }
        acc += __shfl_xor(acc, 1);
        acc += __shfl_xor(acc, 2);
        acc += __shfl_xor(acc, 4);
        acc += __shfl_xor(acc, 8);
        if (seg == 0) qb[b * HIDD + h] = acc + Vb[h];
    } else {
        // convert: 64 blocks x 256 float4 = 16384 float4 = 65536 floats (exact)
        const int c = blk - 512;
        int f4 = c * 256 + tid;
        f32x4 v = *(const f32x4*)(Vw + f4 * 4);
        ushort4 u;
        u.x = f2bf(v.x); u.y = f2bf(v.y); u.z = f2bf(v.z); u.w = f2bf(v.w);
        *(ushort4*)&Vbf[f4 * 4] = u;
    }
}

// ---------------------------------------------------------------------------
// Kernel 2: fused scores + chunk exp-sum + partial context. No max needed:
// |erg| <= ||w_w||_1 + |w_b| <= 11.4, exp is always safe in fp32.
// grid = (NCH, Bn), block = 512 (8 waves; wave w owns h in [16w, 16w+16))
// ---------------------------------------------------------------------------
__global__ __launch_bounds__(512, 8) void attn_main(
    const float* __restrict__ enc, const int* __restrict__ mask,
    const float* __restrict__ qb,  const unsigned short* __restrict__ Vbf,
    const float* __restrict__ ww,  const float* __restrict__ wb,
    float* __restrict__ pW, float* __restrict__ lC, float* __restrict__ ctxP)
{
    __shared__ unsigned short encS[TT * LROW];   // 33280 B
    __shared__ float wpart[8][TT];               // 1024 B

    const int chunk = blockIdx.x, b = blockIdx.y;
    const int tid = threadIdx.x;
    const int t0 = chunk * TT;
    const int wave = tid >> 6, lane = tid & 63;
    const int li = lane & 15, quad = lane >> 4;

    // hoisted scalar/global loads (long latency headroom)
    const int h = wave * 16 + li;
    const float qv = qb[b * HIDD + h];
    const float wv = ww[h];
    const float wbv = wb[0];
    const int mk = (lane < TT) ? mask[b * Tn + t0 + lane] : 1;

    // ---- stage enc tile (16384 floats) -> bf16 LDS, 2 batches of 4 float4 ----
    const float* src = enc + ((size_t)b * Tn + t0) * ENCD;
    #pragma unroll
    for (int batch = 0; batch < 2; ++batch) {
        f32x4 v[4];
        #pragma unroll
        for (int j = 0; j < 4; ++j)
            v[j] = ldnt4(src + ((batch * 4 + j) * 512 + tid) * 4);
        #pragma unroll
        for (int j = 0; j < 4; ++j) {
            int f4 = (batch * 4 + j) * 512 + tid;
            int t = f4 >> 7, e = (f4 & 127) * 4;
            ushort4 u;
            u.x = f2bf(v[j].x); u.y = f2bf(v[j].y);
            u.z = f2bf(v[j].z); u.w = f2bf(v[j].w);
            *(ushort4*)&encS[t * LROW + e] = u;
        }
    }
    __syncthreads();

    // ---- MFMA: k[t, h] for this wave's 16 h, all 32 t ----
    f32x4 acc[2];
    acc[0] = (f32x4){0.f, 0.f, 0.f, 0.f};
    acc[1] = (f32x4){0.f, 0.f, 0.f, 0.f};
    const unsigned short* vrow = Vbf + (size_t)h * ENCD;

    #pragma unroll 4
    for (int ks = 0; ks < 16; ++ks) {
        int k0 = ks * 32 + quad * 8;
        bf16x8 a0 = *(const bf16x8*)&encS[(0  + li) * LROW + k0];
        bf16x8 a1 = *(const bf16x8*)&encS[(16 + li) * LROW + k0];
        bf16x8 bb = *(const bf16x8*)(vrow + k0);
        acc[0] = __builtin_amdgcn_mfma_f32_16x16x32_bf16(a0, bb, acc[0], 0, 0, 0);
        acc[1] = __builtin_amdgcn_mfma_f32_16x16x32_bf16(a1, bb, acc[1], 0, 0, 0);
    }

    // ---- epilogue: s = tanh(k + q)*w_w; reduce over the wave's 16 h ----
    #pragma unroll
    for (int mt = 0; mt < 2; ++mt)
        #pragma unroll
        for (int r = 0; r < 4; ++r) {
            float s = tanh_fast(acc[mt][r] + qv) * wv;
            s += __shfl_xor(s, 1);
            s += __shfl_xor(s, 2);
            s += __shfl_xor(s, 4);
            s += __shfl_xor(s, 8);
            if (li == 0) wpart[wave][mt * 16 + quad * 4 + r] = s;
        }
    __syncthreads();

    // ---- every wave redundantly: p_t = exp(erg_t) in lanes 0..31 ----
    float p = 0.f;
    if (lane < TT) {
        float v = wbv;
        #pragma unroll
        for (int w = 0; w < 8; ++w) v += wpart[w][lane];
        p = (mk != 0) ? 0.f : __expf(v);
    }

    // ---- wave 0: chunk sum + weight partials out ----
    if (wave == 0) {
        float l = p;
        #pragma unroll
        for (int off = 32; off >= 1; off >>= 1)
            l += __shfl_xor(l, off);
        if (lane < TT) pW[(size_t)b * Tn + t0 + lane] = p;
        if (lane == 0) lC[b * NCH + chunk] = l;
    }

    // ---- partial context: ctx[e] = sum_t p[t]*enc[t][e], e = tid ----
    {
        float c = 0.f;
        #pragma unroll
        for (int t = 0; t < TT; ++t) {
            float pt = __shfl(p, t);
            c += pt * bf2f(encS[t * LROW + tid]);
        }
        __builtin_nontemporal_store(c, &ctxP[((size_t)(b * NCH + chunk)) * ENCD + tid]);
    }
}

// ---------------------------------------------------------------------------
// Kernel 3: combine chunks.  grid = (Bn, 5), block = 256
//   part 0..3: context e-range part*128..+128 ; part 4: weights
// ---------------------------------------------------------------------------
__global__ __launch_bounds__(256) void finalize(
    const float* __restrict__ lC, const float* __restrict__ pW,
    const float* __restrict__ ctxP, float* __restrict__ out)
{
    __shared__ float invLs;
    __shared__ float red[256];
    const int b = blockIdx.x, part = blockIdx.y, tid = threadIdx.x;
    const int wave = tid >> 6, lane = tid & 63;

    if (wave == 0) {                             // NCH == 64 == wave width
        float l = lC[b * NCH + lane];
        #pragma unroll
        for (int off = 32; off >= 1; off >>= 1)
            l += __shfl_xor(l, off);
        if (lane == 0) invLs = 1.f / l;
    }
    __syncthreads();
    const float invL = invLs;

    if (part < 4) {
        // context: 2 halves of chunks per thread-half, 128 e-cols
        const int e = part * 128 + (tid & 127);
        const int half = tid >> 7;
        float c = 0.f;
        #pragma unroll 8
        for (int cc = half * 32; cc < half * 32 + 32; ++cc)
            c += ctxP[((size_t)(b * NCH + cc)) * ENCD + e];
        red[tid] = c;
        __syncthreads();
        if (tid < 128) {
            int ee = part * 128 + tid;
            out[b * ENCD + ee] = (red[tid] + red[tid + 128]) * invL;
        }
    } else {
        float* outw = out + Bn * ENCD;
        #pragma unroll
        for (int i = 0; i < 8; ++i) {
            int t = i * 256 + tid;
            outw[(size_t)b * Tn + t] = pW[(size_t)b * Tn + t] * invL;
        }
    }
}

// ---------------------------------------------------------------------------
extern "C" void kernel_launch(void* const* d_in, const int* in_sizes, int n_in,
                              void* d_out, int out_size, void* d_ws, size_t ws_size,
                              hipStream_t stream)
{
    const float* enc  = (const float*)d_in[0];
    const float* dec  = (const float*)d_in[1];
    const int*   mask = (const int*)d_in[2];
    const float* Vw   = (const float*)d_in[3];
    const float* Vb   = (const float*)d_in[4];
    const float* Ww   = (const float*)d_in[5];
    const float* ww   = (const float*)d_in[6];
    const float* wb   = (const float*)d_in[7];
    float* out = (float*)d_out;
    float* ws  = (float*)d_ws;

    // ws layout (float offsets):
    float*          qb   = ws;                               //  8192
    unsigned short* Vbf  = (unsigned short*)(ws + 8192);     // 65536 bf16 = 32768 floats
    float*          pW   = ws + 40960;                       // 131072
    float*          lC   = ws + 172032;                      //   4096
    float*          ctxP = ws + 180224;                      // 2097152  (~9.1 MB total)

    hipLaunchKernelGGL(prep, dim3(576), dim3(256), 0, stream, dec, Ww, Vb, Vw, qb, Vbf);
    hipLaunchKernelGGL(attn_main, dim3(NCH, Bn), dim3(512), 0, stream,
                       enc, mask, qb, Vbf, ww, wb, pW, lC, ctxP);
    hipLaunchKernelGGL(finalize, dim3(Bn, 5), dim3(256), 0, stream, lC, pW, ctxP, out);
}